// Round 18
// baseline (153.296 us; speedup 1.0000x reference)
//
#include <hip/hip_runtime.h>
#include <hip/hip_bf16.h>

#define G_   16
#define DG_  128
#define F_   2048
#define N_   2048
#define M_   2048

typedef __attribute__((ext_vector_type(8))) short s16x8;   // 8 bf16 (4 VGPRs)
typedef __attribute__((ext_vector_type(4))) float f32x4;
typedef __attribute__((ext_vector_type(2))) unsigned int u32x2;

typedef const __attribute__((address_space(1))) void GV;
typedef __attribute__((address_space(3))) void LV;

__device__ inline unsigned short f2bf(float f) {           // RN-even fp32->bf16
  unsigned u = __float_as_uint(f);
  u += 0x7fffu + ((u >> 16) & 1u);
  return (unsigned short)(u >> 16);
}

// ---------------- bf16 NT GEMM from fp32 sources, 3 jobs, 128x128 --------
// R18: fused fp32->bf16 conversion inside staging (cvt5 kernel deleted).
// T14-split: issue 16 global_load_dwordx4 (fp32 A+B, both halves) at tile
// top -> full compute phase of latency cover; at tile end vmcnt(0) ->
// 32 v_cvt_pk_bf16_f32 -> 8 ds_write_b128 to the IDENTICAL swizzled LDS
// layout gload_lds produced (base + lane*16) -> lgkmcnt(0) -> ONE barrier
// per K-tile. Read-side (slot swizzle, ldA/ldB) unchanged from R14.
struct GemmJobs {
  const float* A[3];
  const float* B[3];
  const float* bias[3];
  unsigned short* C[3];
  float osc[3];
};

__global__ __launch_bounds__(256, 2)
void gemm128f(GemmJobs jb) {
  __shared__ __align__(16) char lds[65536];
  const int wg = (blockIdx.x & 7) * 96 + (blockIdx.x >> 3);
  const int j  = wg >> 8;                       // 256 tiles per job
  const int bs = wg & 255;
  const float* A = jb.A[j];
  const float* B = jb.B[j];
  const float* bias = jb.bias[j];
  unsigned short* C = jb.C[j];
  const float osc = jb.osc[j];

  const int tid = threadIdx.x, lane = tid & 63, wv = tid >> 6;  // wv 0..3
  const int wm = wv >> 1, wn = wv & 1;          // 2 x 2 wave grid
  const int l15 = lane & 15, l4 = lane >> 4;
  const int m0 = (bs >> 4) * 128, n0 = (bs & 15) * 128;
  const int slot = (l4 ^ ((l15 >> 1) & 3)) * 16;             // ds_read slot
  const int scol = (((lane & 3) ^ ((lane >> 3) & 3)) * 8);   // staged src col
  const int srow = wv * 16 + (lane >> 2);                    // staged row 0..63
  const int rA = wm * 64 + l15;                              // ds A row base
  const int rB = wn * 64 + l15;                              // ds B row base

  f32x4 acc[4][4];
#pragma unroll
  for (int i = 0; i < 4; ++i)
#pragma unroll
    for (int nf = 0; nf < 4; ++nf) acc[i][nf] = (f32x4){0.f, 0.f, 0.f, 0.f};

  // fp32 per-thread source bases (element units)
  const size_t offA = (size_t)(m0 + srow) * F_ + scol;
  const size_t offB = (size_t)(n0 + srow) * F_ + scol;

  float4 ld[16];   // pending fp32: [h][A rb0(2),rb1(2), B rb0(2),rb1(2)]

  auto issueLoads = [&](int k0) {
#pragma unroll
    for (int h = 0; h < 2; ++h) {
#pragma unroll
      for (int rb = 0; rb < 2; ++rb) {
        const float* pa = A + offA + (size_t)rb * 64 * F_ + k0 + h * 32;
        ld[h * 8 + rb * 2 + 0] = *(const float4*)(pa);
        ld[h * 8 + rb * 2 + 1] = *(const float4*)(pa + 4);
        const float* pb = B + offB + (size_t)rb * 64 * F_ + k0 + h * 32;
        ld[h * 8 + 4 + rb * 2 + 0] = *(const float4*)(pb);
        ld[h * 8 + 4 + rb * 2 + 1] = *(const float4*)(pb + 4);
      }
    }
  };

  auto cvtWrite = [&](int buf2) {
#pragma unroll
    for (int h = 0; h < 2; ++h) {
#pragma unroll
      for (int rb = 0; rb < 2; ++rb) {
#pragma unroll
        for (int mat = 0; mat < 2; ++mat) {      // 0 = A, 1 = B
          float4 x = ld[h * 8 + mat * 4 + rb * 2 + 0];
          float4 y = ld[h * 8 + mat * 4 + rb * 2 + 1];
          uint4 w;
          asm("v_cvt_pk_bf16_f32 %0, %1, %2" : "=v"(w.x) : "v"(x.x), "v"(x.y));
          asm("v_cvt_pk_bf16_f32 %0, %1, %2" : "=v"(w.y) : "v"(x.z), "v"(x.w));
          asm("v_cvt_pk_bf16_f32 %0, %1, %2" : "=v"(w.z) : "v"(y.x), "v"(y.y));
          asm("v_cvt_pk_bf16_f32 %0, %1, %2" : "=v"(w.w) : "v"(y.z), "v"(y.w));
          *(uint4*)(lds + buf2 * 32768 + mat * 16384 + h * 8192 + rb * 4096 +
                    wv * 1024 + lane * 16) = w;
        }
      }
    }
  };

  // prologue: tile 0
  issueLoads(0);
  asm volatile("s_waitcnt vmcnt(0)" ::: "memory");
  cvtWrite(0);
  asm volatile("s_waitcnt lgkmcnt(0)" ::: "memory");
  __builtin_amdgcn_sched_barrier(0);
  __builtin_amdgcn_s_barrier();

  const int NT = F_ / 64;
  for (int t = 0; t < NT; ++t) {
    const int buf = t & 1;
    const char* Lb = lds + buf * 32768;
    const bool pf = (t + 1 < NT);
    s16x8 af[4], bf[4];

    auto ldA = [&](int mf, int h) {
      return *(const s16x8*)(Lb + h * 8192 + (rA + mf * 16) * 64 + slot);
    };
    auto ldB = [&](int nf, int h) {
      return *(const s16x8*)(Lb + 16384 + h * 8192 + (rB + nf * 16) * 64 + slot);
    };

    // issue next tile's fp32 loads — whole compute phase of latency cover
    if (pf) issueLoads((t + 1) * 64);
    __builtin_amdgcn_sched_barrier(0);

    // ---- half 0 ----
#pragma unroll
    for (int nf = 0; nf < 4; ++nf) bf[nf] = ldB(nf, 0);
#pragma unroll
    for (int i = 0; i < 4; ++i) af[i] = ldA(i, 0);
    asm volatile("s_waitcnt lgkmcnt(0)" ::: "memory");
    __builtin_amdgcn_sched_barrier(0);
    __builtin_amdgcn_s_setprio(1);
#pragma unroll
    for (int i = 0; i < 4; ++i)
#pragma unroll
      for (int nf = 0; nf < 4; ++nf)
        acc[i][nf] = __builtin_amdgcn_mfma_f32_16x16x32_bf16(af[i], bf[nf], acc[i][nf], 0, 0, 0);
    __builtin_amdgcn_s_setprio(0);

    // ---- half 1 ----
#pragma unroll
    for (int nf = 0; nf < 4; ++nf) bf[nf] = ldB(nf, 1);
#pragma unroll
    for (int i = 0; i < 4; ++i) af[i] = ldA(i, 1);
    asm volatile("s_waitcnt lgkmcnt(0)" ::: "memory");
    __builtin_amdgcn_sched_barrier(0);
    __builtin_amdgcn_s_setprio(1);
#pragma unroll
    for (int i = 0; i < 4; ++i)
#pragma unroll
      for (int nf = 0; nf < 4; ++nf)
        acc[i][nf] = __builtin_amdgcn_mfma_f32_16x16x32_bf16(af[i], bf[nf], acc[i][nf], 0, 0, 0);
    __builtin_amdgcn_s_setprio(0);

    // ---- tile end: land loads, convert+write into buf^1, one barrier ----
    if (pf) {
      asm volatile("s_waitcnt vmcnt(0)" ::: "memory");
      __builtin_amdgcn_sched_barrier(0);
      cvtWrite(buf ^ 1);
      asm volatile("s_waitcnt lgkmcnt(0)" ::: "memory");
    }
    __builtin_amdgcn_sched_barrier(0);
    __builtin_amdgcn_s_barrier();
  }

  // ---- epilogue ----
#pragma unroll
  for (int nf = 0; nf < 4; ++nf) {
    int c = n0 + wn * 64 + nf * 16 + l15;
    float bv = bias ? bias[c] : 0.f;
#pragma unroll
    for (int mf = 0; mf < 4; ++mf) {
#pragma unroll
      for (int jj = 0; jj < 4; ++jj) {
        int r = m0 + wm * 64 + mf * 16 + l4 * 4 + jj;
        C[(size_t)r * F_ + c] = f2bf((acc[mf][nf][jj] + bv) * osc);
      }
    }
  }
}

// ---------------- flash attention v1 (R6/R16 exact, 2D grid) -------------
__global__ __launch_bounds__(256, 2)
void attn_mfma(const unsigned short* __restrict__ Q,
               const unsigned short* __restrict__ K,
               const unsigned short* __restrict__ Vt,
               const float* __restrict__ vb,
               float* __restrict__ out) {
  __shared__ unsigned short Kt[2][64 * 128];
  __shared__ unsigned short Vts[2][128 * 64];
  __shared__ unsigned short Pt[4][16 * 64];
  const int tid = threadIdx.x, lane = tid & 63, wv = tid >> 6;
  const int l15 = lane & 15, l4 = lane >> 4;
  const int g = blockIdx.y;
  const int q0 = blockIdx.x * 64 + wv * 16;

  s16x8 qa[4];
#pragma unroll
  for (int kc = 0; kc < 4; ++kc)
    qa[kc] = *(const s16x8*)(Q + (size_t)(q0 + l15) * F_ + g * DG_ + kc * 32 + l4 * 8);

  f32x4 oa[8];
#pragma unroll
  for (int df = 0; df < 8; ++df) oa[df] = (f32x4){0.f, 0.f, 0.f, 0.f};
  float m_r = -1e30f, l_r = 0.f;

  const int ksw0 = (((lane & 15) ^ (lane >> 4)) * 8);
  const int ksw1 = (((lane & 15) ^ 4 ^ (lane >> 4)) * 8);
  const int vsw  = (((lane & 7) ^ (lane >> 3)) * 8);
  const int xorb = (l15 & 7) << 4;
  int csw[4];
#pragma unroll
  for (int kc = 0; kc < 4; ++kc) csw[kc] = (kc * 64 + l4 * 16) ^ xorb;

  auto stage = [&](int buf, int kv0) {
#pragma unroll
    for (int i = 0; i < 4; ++i) {   // K tile: 4 rows (256B) per instr
      int r0 = wv * 16 + i * 4;
      __builtin_amdgcn_global_load_lds(
          (GV*)(K + (size_t)(kv0 + r0 + (lane >> 4)) * F_ + g * DG_ + ((i & 1) ? ksw1 : ksw0)),
          (LV*)(&Kt[buf][r0 * 128]), 16, 0, 0);
    }
#pragma unroll
    for (int i = 0; i < 4; ++i) {   // V^T tile: 8 rows (128B) per instr
      int r0 = wv * 32 + i * 8;
      __builtin_amdgcn_global_load_lds(
          (GV*)(Vt + (size_t)(g * DG_ + r0 + (lane >> 3)) * M_ + kv0 + vsw),
          (LV*)(&Vts[buf][r0 * 64]), 16, 0, 0);
    }
  };

  stage(0, 0);
  __syncthreads();
  int cur = 0;
  unsigned short* Pw = &Pt[wv][0];

  for (int t = 0; t < M_ / 64; ++t) {
    if (t + 1 < M_ / 64) stage(cur ^ 1, (t + 1) * 64);
    const unsigned short* Kb = &Kt[cur][0];
    const unsigned short* Vb = &Vts[cur][0];

    // ---- S^T = K Q^T : lane q=l15, kv = kvf*16 + l4*4 + j (log2 domain) --
    f32x4 sf[4];
    __builtin_amdgcn_s_setprio(1);
#pragma unroll
    for (int kvf = 0; kvf < 4; ++kvf) {
      f32x4 s = (f32x4){0.f, 0.f, 0.f, 0.f};
#pragma unroll
      for (int kc = 0; kc < 4; ++kc) {
        s16x8 kf = *(const s16x8*)((const char*)Kb + (kvf * 16 + l15) * 256 + csw[kc]);
        s = __builtin_amdgcn_mfma_f32_16x16x32_bf16(kf, qa[kc], s, 0, 0, 0);
      }
      sf[kvf] = s;
    }
    __builtin_amdgcn_s_setprio(0);

    // ---- online softmax with defer-max (THR=8, log2 domain) ----
    float tmax = sf[0][0];
#pragma unroll
    for (int kvf = 0; kvf < 4; ++kvf) {
      tmax = fmaxf(tmax, fmaxf(fmaxf(sf[kvf][0], sf[kvf][1]),
                               fmaxf(sf[kvf][2], sf[kvf][3])));
    }
    tmax = fmaxf(tmax, __shfl_xor(tmax, 16));
    tmax = fmaxf(tmax, __shfl_xor(tmax, 32));
    if (!__all(tmax <= m_r + 8.0f)) {
      float mnew = fmaxf(m_r, tmax);
      float corr = __builtin_amdgcn_exp2f(m_r - mnew);
      m_r = mnew;
      l_r *= corr;
      float c0 = __shfl(corr, l4 * 4 + 0);
      float c1 = __shfl(corr, l4 * 4 + 1);
      float c2 = __shfl(corr, l4 * 4 + 2);
      float c3 = __shfl(corr, l4 * 4 + 3);
#pragma unroll
      for (int df = 0; df < 8; ++df) {
        oa[df][0] *= c0; oa[df][1] *= c1; oa[df][2] *= c2; oa[df][3] *= c3;
      }
    }

    float psum = 0.f;
#pragma unroll
    for (int kvf = 0; kvf < 4; ++kvf) {
      float p0 = __builtin_amdgcn_exp2f(sf[kvf][0] - m_r);
      float p1 = __builtin_amdgcn_exp2f(sf[kvf][1] - m_r);
      float p2 = __builtin_amdgcn_exp2f(sf[kvf][2] - m_r);
      float p3 = __builtin_amdgcn_exp2f(sf[kvf][3] - m_r);
      psum += (p0 + p1) + (p2 + p3);
      u32x2 w;
      asm("v_cvt_pk_bf16_f32 %0, %1, %2" : "=v"(w.x) : "v"(p0), "v"(p1));
      asm("v_cvt_pk_bf16_f32 %0, %1, %2" : "=v"(w.y) : "v"(p2), "v"(p3));
      *(u32x2*)((char*)Pw + l15 * 128 + ((kvf * 32 + l4 * 8) ^ xorb)) = w;
    }
    psum += __shfl_xor(psum, 16);
    psum += __shfl_xor(psum, 32);
    l_r += psum;

    // ---- O += P V : A = P rows (q=l15), B = V^T rows (d) ----
    s16x8 pa0 = *(const s16x8*)((const char*)Pw + l15 * 128 + csw[0]);
    s16x8 pa1 = *(const s16x8*)((const char*)Pw + l15 * 128 + csw[1]);
    __builtin_amdgcn_s_setprio(1);
#pragma unroll
    for (int df = 0; df < 8; ++df) {
      s16x8 v0 = *(const s16x8*)((const char*)Vb + (df * 16 + l15) * 128 + csw[0]);
      s16x8 v1 = *(const s16x8*)((const char*)Vb + (df * 16 + l15) * 128 + csw[1]);
      oa[df] = __builtin_amdgcn_mfma_f32_16x16x32_bf16(pa0, v0, oa[df], 0, 0, 0);
      oa[df] = __builtin_amdgcn_mfma_f32_16x16x32_bf16(pa1, v1, oa[df], 0, 0, 0);
    }
    __builtin_amdgcn_s_setprio(0);
    __syncthreads();
    cur ^= 1;
  }

  // ---- epilogue ----
  float linv = 1.0f / l_r;
  float i0 = __shfl(linv, l4 * 4 + 0);
  float i1 = __shfl(linv, l4 * 4 + 1);
  float i2 = __shfl(linv, l4 * 4 + 2);
  float i3 = __shfl(linv, l4 * 4 + 3);
#pragma unroll
  for (int df = 0; df < 8; ++df) {
    int c = g * DG_ + df * 16 + l15;
    float bv = vb[c];
    out[(size_t)(q0 + l4 * 4 + 0) * F_ + c] = oa[df][0] * i0 + bv;
    out[(size_t)(q0 + l4 * 4 + 1) * F_ + c] = oa[df][1] * i1 + bv;
    out[(size_t)(q0 + l4 * 4 + 2) * F_ + c] = oa[df][2] * i2 + bv;
    out[(size_t)(q0 + l4 * 4 + 3) * F_ + c] = oa[df][3] * i3 + bv;
  }
}

extern "C" void kernel_launch(void* const* d_in, const int* in_sizes, int n_in,
                              void* d_out, int out_size, void* d_ws, size_t ws_size,
                              hipStream_t stream) {
  const float* roi  = (const float*)d_in[0];
  const float* ref  = (const float*)d_in[1];
  const float* Wq_w = (const float*)d_in[2];
  const float* Wq_b = (const float*)d_in[3];
  const float* Wk_w = (const float*)d_in[4];
  const float* Wk_b = (const float*)d_in[5];
  const float* Wv_w = (const float*)d_in[6];
  const float* Wv_b = (const float*)d_in[7];
  float* out = (float*)d_out;
  const size_t SEG = 4194304;  // 8 MB / 2B
  const float cscale = 0.12751664508246770f;  // (1/sqrt(128)) * log2(e)

  if (ws_size < 24ull * 1024 * 1024) return;
  unsigned short* Qb  = (unsigned short*)d_ws;
  unsigned short* Kb  = Qb + SEG;
  unsigned short* Vtb = Kb + SEG;

  GemmJobs jb;
  jb.A[0] = roi;  jb.B[0] = Wq_w; jb.bias[0] = Wq_b;    jb.C[0] = Qb;  jb.osc[0] = cscale;
  jb.A[1] = ref;  jb.B[1] = Wk_w; jb.bias[1] = Wk_b;    jb.C[1] = Kb;  jb.osc[1] = 1.0f;
  jb.A[2] = Wv_w; jb.B[2] = ref;  jb.bias[2] = nullptr; jb.C[2] = Vtb; jb.osc[2] = 1.0f;
  gemm128f<<<768, 256, 0, stream>>>(jb);

  attn_mfma<<<dim3(N_ / 64, G_), 256, 0, stream>>>(Qb, Kb, Vtb, Wv_b, out);
}

// Round 19
// 152.554 us; speedup vs baseline: 1.0049x; 1.0049x over previous
//
#include <hip/hip_runtime.h>
#include <hip/hip_bf16.h>

#define G_   16
#define DG_  128
#define F_   2048
#define N_   2048
#define M_   2048

typedef __attribute__((ext_vector_type(8))) short s16x8;   // 8 bf16 (4 VGPRs)
typedef __attribute__((ext_vector_type(4))) float f32x4;
typedef __attribute__((ext_vector_type(2))) unsigned int u32x2;

typedef const __attribute__((address_space(1))) void GV;
typedef __attribute__((address_space(3))) void LV;

__device__ inline unsigned short f2bf(float f) {           // RN-even fp32->bf16
  unsigned u = __float_as_uint(f);
  u += 0x7fffu + ((u >> 16) & 1u);
  return (unsigned short)(u >> 16);
}

// ---------------- bf16 NT GEMM from fp32 sources, 3 jobs, 128x128 --------
// R18: fused fp32->bf16 conversion inside staging (cvt5 kernel deleted).
// T14-split: issue 16 global_load_dwordx4 (fp32 A+B, both halves) at tile
// top -> full compute phase of latency cover; at tile end vmcnt(0) ->
// 32 v_cvt_pk_bf16_f32 -> 8 ds_write_b128 to the IDENTICAL swizzled LDS
// layout gload_lds produced (base + lane*16) -> lgkmcnt(0) -> ONE barrier
// per K-tile. Read-side (slot swizzle, ldA/ldB) unchanged from R14.
struct GemmJobs {
  const float* A[3];
  const float* B[3];
  const float* bias[3];
  unsigned short* C[3];
  float osc[3];
};

__global__ __launch_bounds__(256, 2)
void gemm128f(GemmJobs jb) {
  __shared__ __align__(16) char lds[65536];
  const int wg = (blockIdx.x & 7) * 96 + (blockIdx.x >> 3);
  const int j  = wg >> 8;                       // 256 tiles per job
  const int bs = wg & 255;
  const float* A = jb.A[j];
  const float* B = jb.B[j];
  const float* bias = jb.bias[j];
  unsigned short* C = jb.C[j];
  const float osc = jb.osc[j];

  const int tid = threadIdx.x, lane = tid & 63, wv = tid >> 6;  // wv 0..3
  const int wm = wv >> 1, wn = wv & 1;          // 2 x 2 wave grid
  const int l15 = lane & 15, l4 = lane >> 4;
  const int m0 = (bs >> 4) * 128, n0 = (bs & 15) * 128;
  const int slot = (l4 ^ ((l15 >> 1) & 3)) * 16;             // ds_read slot
  const int scol = (((lane & 3) ^ ((lane >> 3) & 3)) * 8);   // staged src col
  const int srow = wv * 16 + (lane >> 2);                    // staged row 0..63
  const int rA = wm * 64 + l15;                              // ds A row base
  const int rB = wn * 64 + l15;                              // ds B row base

  f32x4 acc[4][4];
#pragma unroll
  for (int i = 0; i < 4; ++i)
#pragma unroll
    for (int nf = 0; nf < 4; ++nf) acc[i][nf] = (f32x4){0.f, 0.f, 0.f, 0.f};

  // fp32 per-thread source bases (element units)
  const size_t offA = (size_t)(m0 + srow) * F_ + scol;
  const size_t offB = (size_t)(n0 + srow) * F_ + scol;

  float4 ld[16];   // pending fp32: [h][A rb0(2),rb1(2), B rb0(2),rb1(2)]

  auto issueLoads = [&](int k0) {
#pragma unroll
    for (int h = 0; h < 2; ++h) {
#pragma unroll
      for (int rb = 0; rb < 2; ++rb) {
        const float* pa = A + offA + (size_t)rb * 64 * F_ + k0 + h * 32;
        ld[h * 8 + rb * 2 + 0] = *(const float4*)(pa);
        ld[h * 8 + rb * 2 + 1] = *(const float4*)(pa + 4);
        const float* pb = B + offB + (size_t)rb * 64 * F_ + k0 + h * 32;
        ld[h * 8 + 4 + rb * 2 + 0] = *(const float4*)(pb);
        ld[h * 8 + 4 + rb * 2 + 1] = *(const float4*)(pb + 4);
      }
    }
  };

  auto cvtWrite = [&](int buf2) {
#pragma unroll
    for (int h = 0; h < 2; ++h) {
#pragma unroll
      for (int rb = 0; rb < 2; ++rb) {
#pragma unroll
        for (int mat = 0; mat < 2; ++mat) {      // 0 = A, 1 = B
          float4 x = ld[h * 8 + mat * 4 + rb * 2 + 0];
          float4 y = ld[h * 8 + mat * 4 + rb * 2 + 1];
          uint4 w;
          asm("v_cvt_pk_bf16_f32 %0, %1, %2" : "=v"(w.x) : "v"(x.x), "v"(x.y));
          asm("v_cvt_pk_bf16_f32 %0, %1, %2" : "=v"(w.y) : "v"(x.z), "v"(x.w));
          asm("v_cvt_pk_bf16_f32 %0, %1, %2" : "=v"(w.z) : "v"(y.x), "v"(y.y));
          asm("v_cvt_pk_bf16_f32 %0, %1, %2" : "=v"(w.w) : "v"(y.z), "v"(y.w));
          *(uint4*)(lds + buf2 * 32768 + mat * 16384 + h * 8192 + rb * 4096 +
                    wv * 1024 + lane * 16) = w;
        }
      }
    }
  };

  // prologue: tile 0
  issueLoads(0);
  asm volatile("s_waitcnt vmcnt(0)" ::: "memory");
  cvtWrite(0);
  asm volatile("s_waitcnt lgkmcnt(0)" ::: "memory");
  __builtin_amdgcn_sched_barrier(0);
  __builtin_amdgcn_s_barrier();

  const int NT = F_ / 64;
  for (int t = 0; t < NT; ++t) {
    const int buf = t & 1;
    const char* Lb = lds + buf * 32768;
    const bool pf = (t + 1 < NT);
    s16x8 af[4], bf[4];

    auto ldA = [&](int mf, int h) {
      return *(const s16x8*)(Lb + h * 8192 + (rA + mf * 16) * 64 + slot);
    };
    auto ldB = [&](int nf, int h) {
      return *(const s16x8*)(Lb + 16384 + h * 8192 + (rB + nf * 16) * 64 + slot);
    };

    // issue next tile's fp32 loads — whole compute phase of latency cover
    if (pf) issueLoads((t + 1) * 64);
    __builtin_amdgcn_sched_barrier(0);

    // ---- half 0 ----
#pragma unroll
    for (int nf = 0; nf < 4; ++nf) bf[nf] = ldB(nf, 0);
#pragma unroll
    for (int i = 0; i < 4; ++i) af[i] = ldA(i, 0);
    asm volatile("s_waitcnt lgkmcnt(0)" ::: "memory");
    __builtin_amdgcn_sched_barrier(0);
    __builtin_amdgcn_s_setprio(1);
#pragma unroll
    for (int i = 0; i < 4; ++i)
#pragma unroll
      for (int nf = 0; nf < 4; ++nf)
        acc[i][nf] = __builtin_amdgcn_mfma_f32_16x16x32_bf16(af[i], bf[nf], acc[i][nf], 0, 0, 0);
    __builtin_amdgcn_s_setprio(0);

    // ---- half 1 ----
#pragma unroll
    for (int nf = 0; nf < 4; ++nf) bf[nf] = ldB(nf, 1);
#pragma unroll
    for (int i = 0; i < 4; ++i) af[i] = ldA(i, 1);
    asm volatile("s_waitcnt lgkmcnt(0)" ::: "memory");
    __builtin_amdgcn_sched_barrier(0);
    __builtin_amdgcn_s_setprio(1);
#pragma unroll
    for (int i = 0; i < 4; ++i)
#pragma unroll
      for (int nf = 0; nf < 4; ++nf)
        acc[i][nf] = __builtin_amdgcn_mfma_f32_16x16x32_bf16(af[i], bf[nf], acc[i][nf], 0, 0, 0);
    __builtin_amdgcn_s_setprio(0);

    // ---- tile end: land loads, convert+write into buf^1, one barrier ----
    if (pf) {
      asm volatile("s_waitcnt vmcnt(0)" ::: "memory");
      __builtin_amdgcn_sched_barrier(0);
      cvtWrite(buf ^ 1);
      asm volatile("s_waitcnt lgkmcnt(0)" ::: "memory");
    }
    __builtin_amdgcn_sched_barrier(0);
    __builtin_amdgcn_s_barrier();
  }

  // ---- epilogue ----
#pragma unroll
  for (int nf = 0; nf < 4; ++nf) {
    int c = n0 + wn * 64 + nf * 16 + l15;
    float bv = bias ? bias[c] : 0.f;
#pragma unroll
    for (int mf = 0; mf < 4; ++mf) {
#pragma unroll
      for (int jj = 0; jj < 4; ++jj) {
        int r = m0 + wm * 64 + mf * 16 + l4 * 4 + jj;
        C[(size_t)r * F_ + c] = f2bf((acc[mf][nf][jj] + bv) * osc);
      }
    }
  }
}

// ---------------- flash attention v1 (R6/R16 exact, 2D grid) -------------
__global__ __launch_bounds__(256, 2)
void attn_mfma(const unsigned short* __restrict__ Q,
               const unsigned short* __restrict__ K,
               const unsigned short* __restrict__ Vt,
               const float* __restrict__ vb,
               float* __restrict__ out) {
  __shared__ unsigned short Kt[2][64 * 128];
  __shared__ unsigned short Vts[2][128 * 64];
  __shared__ unsigned short Pt[4][16 * 64];
  const int tid = threadIdx.x, lane = tid & 63, wv = tid >> 6;
  const int l15 = lane & 15, l4 = lane >> 4;
  const int g = blockIdx.y;
  const int q0 = blockIdx.x * 64 + wv * 16;

  s16x8 qa[4];
#pragma unroll
  for (int kc = 0; kc < 4; ++kc)
    qa[kc] = *(const s16x8*)(Q + (size_t)(q0 + l15) * F_ + g * DG_ + kc * 32 + l4 * 8);

  f32x4 oa[8];
#pragma unroll
  for (int df = 0; df < 8; ++df) oa[df] = (f32x4){0.f, 0.f, 0.f, 0.f};
  float m_r = -1e30f, l_r = 0.f;

  const int ksw0 = (((lane & 15) ^ (lane >> 4)) * 8);
  const int ksw1 = (((lane & 15) ^ 4 ^ (lane >> 4)) * 8);
  const int vsw  = (((lane & 7) ^ (lane >> 3)) * 8);
  const int xorb = (l15 & 7) << 4;
  int csw[4];
#pragma unroll
  for (int kc = 0; kc < 4; ++kc) csw[kc] = (kc * 64 + l4 * 16) ^ xorb;

  auto stage = [&](int buf, int kv0) {
#pragma unroll
    for (int i = 0; i < 4; ++i) {   // K tile: 4 rows (256B) per instr
      int r0 = wv * 16 + i * 4;
      __builtin_amdgcn_global_load_lds(
          (GV*)(K + (size_t)(kv0 + r0 + (lane >> 4)) * F_ + g * DG_ + ((i & 1) ? ksw1 : ksw0)),
          (LV*)(&Kt[buf][r0 * 128]), 16, 0, 0);
    }
#pragma unroll
    for (int i = 0; i < 4; ++i) {   // V^T tile: 8 rows (128B) per instr
      int r0 = wv * 32 + i * 8;
      __builtin_amdgcn_global_load_lds(
          (GV*)(Vt + (size_t)(g * DG_ + r0 + (lane >> 3)) * M_ + kv0 + vsw),
          (LV*)(&Vts[buf][r0 * 64]), 16, 0, 0);
    }
  };

  stage(0, 0);
  __syncthreads();
  int cur = 0;
  unsigned short* Pw = &Pt[wv][0];

  for (int t = 0; t < M_ / 64; ++t) {
    if (t + 1 < M_ / 64) stage(cur ^ 1, (t + 1) * 64);
    const unsigned short* Kb = &Kt[cur][0];
    const unsigned short* Vb = &Vts[cur][0];

    // ---- S^T = K Q^T : lane q=l15, kv = kvf*16 + l4*4 + j (log2 domain) --
    f32x4 sf[4];
    __builtin_amdgcn_s_setprio(1);
#pragma unroll
    for (int kvf = 0; kvf < 4; ++kvf) {
      f32x4 s = (f32x4){0.f, 0.f, 0.f, 0.f};
#pragma unroll
      for (int kc = 0; kc < 4; ++kc) {
        s16x8 kf = *(const s16x8*)((const char*)Kb + (kvf * 16 + l15) * 256 + csw[kc]);
        s = __builtin_amdgcn_mfma_f32_16x16x32_bf16(kf, qa[kc], s, 0, 0, 0);
      }
      sf[kvf] = s;
    }
    __builtin_amdgcn_s_setprio(0);

    // ---- online softmax with defer-max (THR=8, log2 domain) ----
    float tmax = sf[0][0];
#pragma unroll
    for (int kvf = 0; kvf < 4; ++kvf) {
      tmax = fmaxf(tmax, fmaxf(fmaxf(sf[kvf][0], sf[kvf][1]),
                               fmaxf(sf[kvf][2], sf[kvf][3])));
    }
    tmax = fmaxf(tmax, __shfl_xor(tmax, 16));
    tmax = fmaxf(tmax, __shfl_xor(tmax, 32));
    if (!__all(tmax <= m_r + 8.0f)) {
      float mnew = fmaxf(m_r, tmax);
      float corr = __builtin_amdgcn_exp2f(m_r - mnew);
      m_r = mnew;
      l_r *= corr;
      float c0 = __shfl(corr, l4 * 4 + 0);
      float c1 = __shfl(corr, l4 * 4 + 1);
      float c2 = __shfl(corr, l4 * 4 + 2);
      float c3 = __shfl(corr, l4 * 4 + 3);
#pragma unroll
      for (int df = 0; df < 8; ++df) {
        oa[df][0] *= c0; oa[df][1] *= c1; oa[df][2] *= c2; oa[df][3] *= c3;
      }
    }

    float psum = 0.f;
#pragma unroll
    for (int kvf = 0; kvf < 4; ++kvf) {
      float p0 = __builtin_amdgcn_exp2f(sf[kvf][0] - m_r);
      float p1 = __builtin_amdgcn_exp2f(sf[kvf][1] - m_r);
      float p2 = __builtin_amdgcn_exp2f(sf[kvf][2] - m_r);
      float p3 = __builtin_amdgcn_exp2f(sf[kvf][3] - m_r);
      psum += (p0 + p1) + (p2 + p3);
      u32x2 w;
      asm("v_cvt_pk_bf16_f32 %0, %1, %2" : "=v"(w.x) : "v"(p0), "v"(p1));
      asm("v_cvt_pk_bf16_f32 %0, %1, %2" : "=v"(w.y) : "v"(p2), "v"(p3));
      *(u32x2*)((char*)Pw + l15 * 128 + ((kvf * 32 + l4 * 8) ^ xorb)) = w;
    }
    psum += __shfl_xor(psum, 16);
    psum += __shfl_xor(psum, 32);
    l_r += psum;

    // ---- O += P V : A = P rows (q=l15), B = V^T rows (d) ----
    s16x8 pa0 = *(const s16x8*)((const char*)Pw + l15 * 128 + csw[0]);
    s16x8 pa1 = *(const s16x8*)((const char*)Pw + l15 * 128 + csw[1]);
    __builtin_amdgcn_s_setprio(1);
#pragma unroll
    for (int df = 0; df < 8; ++df) {
      s16x8 v0 = *(const s16x8*)((const char*)Vb + (df * 16 + l15) * 128 + csw[0]);
      s16x8 v1 = *(const s16x8*)((const char*)Vb + (df * 16 + l15) * 128 + csw[1]);
      oa[df] = __builtin_amdgcn_mfma_f32_16x16x32_bf16(pa0, v0, oa[df], 0, 0, 0);
      oa[df] = __builtin_amdgcn_mfma_f32_16x16x32_bf16(pa1, v1, oa[df], 0, 0, 0);
    }
    __builtin_amdgcn_s_setprio(0);
    __syncthreads();
    cur ^= 1;
  }

  // ---- epilogue ----
  float linv = 1.0f / l_r;
  float i0 = __shfl(linv, l4 * 4 + 0);
  float i1 = __shfl(linv, l4 * 4 + 1);
  float i2 = __shfl(linv, l4 * 4 + 2);
  float i3 = __shfl(linv, l4 * 4 + 3);
#pragma unroll
  for (int df = 0; df < 8; ++df) {
    int c = g * DG_ + df * 16 + l15;
    float bv = vb[c];
    out[(size_t)(q0 + l4 * 4 + 0) * F_ + c] = oa[df][0] * i0 + bv;
    out[(size_t)(q0 + l4 * 4 + 1) * F_ + c] = oa[df][1] * i1 + bv;
    out[(size_t)(q0 + l4 * 4 + 2) * F_ + c] = oa[df][2] * i2 + bv;
    out[(size_t)(q0 + l4 * 4 + 3) * F_ + c] = oa[df][3] * i3 + bv;
  }
}

extern "C" void kernel_launch(void* const* d_in, const int* in_sizes, int n_in,
                              void* d_out, int out_size, void* d_ws, size_t ws_size,
                              hipStream_t stream) {
  const float* roi  = (const float*)d_in[0];
  const float* ref  = (const float*)d_in[1];
  const float* Wq_w = (const float*)d_in[2];
  const float* Wq_b = (const float*)d_in[3];
  const float* Wk_w = (const float*)d_in[4];
  const float* Wk_b = (const float*)d_in[5];
  const float* Wv_w = (const float*)d_in[6];
  const float* Wv_b = (const float*)d_in[7];
  float* out = (float*)d_out;
  const size_t SEG = 4194304;  // 8 MB / 2B
  const float cscale = 0.12751664508246770f;  // (1/sqrt(128)) * log2(e)

  if (ws_size < 24ull * 1024 * 1024) return;
  unsigned short* Qb  = (unsigned short*)d_ws;
  unsigned short* Kb  = Qb + SEG;
  unsigned short* Vtb = Kb + SEG;

  GemmJobs jb;
  jb.A[0] = roi;  jb.B[0] = Wq_w; jb.bias[0] = Wq_b;    jb.C[0] = Qb;  jb.osc[0] = cscale;
  jb.A[1] = ref;  jb.B[1] = Wk_w; jb.bias[1] = Wk_b;    jb.C[1] = Kb;  jb.osc[1] = 1.0f;
  jb.A[2] = Wv_w; jb.B[2] = ref;  jb.bias[2] = nullptr; jb.C[2] = Vtb; jb.osc[2] = 1.0f;
  gemm128f<<<768, 256, 0, stream>>>(jb);

  attn_mfma<<<dim3(N_ / 64, G_), 256, 0, stream>>>(Qb, Kb, Vtb, Wv_b, out);
}

// Round 20
// 138.985 us; speedup vs baseline: 1.1030x; 1.0976x over previous
//
#include <hip/hip_runtime.h>
#include <hip/hip_bf16.h>

#define G_   16
#define DG_  128
#define F_   2048
#define N_   2048
#define M_   2048

typedef __attribute__((ext_vector_type(8))) short s16x8;   // 8 bf16 (4 VGPRs)
typedef __attribute__((ext_vector_type(4))) float f32x4;
typedef __attribute__((ext_vector_type(2))) unsigned int u32x2;

typedef const __attribute__((address_space(1))) void GV;
typedef __attribute__((address_space(3))) void LV;

__device__ inline unsigned short f2bf(float f) {           // RN-even fp32->bf16
  unsigned u = __float_as_uint(f);
  u += 0x7fffu + ((u >> 16) & 1u);
  return (unsigned short)(u >> 16);
}

// ---------------- fp32 -> bf16 convert: 5 arrays in one launch -----------
struct Cvt5Args { const float* s[5]; unsigned short* d[5]; };

__global__ __launch_bounds__(256)
void cvt5(Cvt5Args a) {
  unsigned u = blockIdx.x * 256 + threadIdx.x;
  if (u >= 5u * 524288u) return;
  int seg = u >> 19;                 // 524288 = 2^19 eights per 4M array
  unsigned off = u & 524287u;
  const float4* sp = (const float4*)(a.s[seg] + (size_t)off * 8);
  float4 x = sp[0], y = sp[1];
  uint4 o;
  o.x = (unsigned)f2bf(x.x) | ((unsigned)f2bf(x.y) << 16);
  o.y = (unsigned)f2bf(x.z) | ((unsigned)f2bf(x.w) << 16);
  o.z = (unsigned)f2bf(y.x) | ((unsigned)f2bf(y.y) << 16);
  o.w = (unsigned)f2bf(y.z) | ((unsigned)f2bf(y.w) << 16);
  *(uint4*)(a.d[seg] + (size_t)off * 8) = o;
}

// ---------------- bf16 NT GEMM, 3 jobs, 128x128, 768 blocks --------------
// (R14 structure, best-measured: 2 blocks/CU, counted-vmcnt ring,
// conflict-free 64B-row swizzle, XCD-aware block swizzle.)
struct GemmJobs {
  const unsigned short* A[3];
  const unsigned short* B[3];
  const float* bias[3];
  unsigned short* C[3];
  float osc[3];
};

__global__ __launch_bounds__(256, 2)
void gemm128(GemmJobs jb) {
  __shared__ __align__(16) char lds[65536];
  const int wg = (blockIdx.x & 7) * 96 + (blockIdx.x >> 3);
  const int j  = wg >> 8;                       // 256 tiles per job
  const int bs = wg & 255;
  const unsigned short* A = jb.A[j];
  const unsigned short* B = jb.B[j];
  const float* bias = jb.bias[j];
  unsigned short* C = jb.C[j];
  const float osc = jb.osc[j];

  const int tid = threadIdx.x, lane = tid & 63, wv = tid >> 6;  // wv 0..3
  const int wm = wv >> 1, wn = wv & 1;          // 2 x 2 wave grid
  const int l15 = lane & 15, l4 = lane >> 4;
  const int m0 = (bs >> 4) * 128, n0 = (bs & 15) * 128;
  const int slot = (l4 ^ ((l15 >> 1) & 3)) * 16;             // ds_read slot
  const int scol = (((lane & 3) ^ ((lane >> 3) & 3)) * 8);   // staged src col
  const int srow = wv * 16 + (lane >> 2);                    // staged row 0..63
  const int rA = wm * 64 + l15;                              // ds A row base
  const int rB = wn * 64 + l15;                              // ds B row base

  f32x4 acc[4][4];
#pragma unroll
  for (int i = 0; i < 4; ++i)
#pragma unroll
    for (int nf = 0; nf < 4; ++nf) acc[i][nf] = (f32x4){0.f, 0.f, 0.f, 0.f};

  auto stage_kh = [&](int buf2, int h, int k0) {
#pragma unroll
    for (int rb = 0; rb < 2; ++rb) {
      __builtin_amdgcn_global_load_lds(
          (GV*)(A + (size_t)(m0 + rb * 64 + srow) * F_ + k0 + h * 32 + scol),
          (LV*)(lds + buf2 * 32768 + h * 8192 + rb * 4096 + wv * 1024),
          16, 0, 0);
      __builtin_amdgcn_global_load_lds(
          (GV*)(B + (size_t)(n0 + rb * 64 + srow) * F_ + k0 + h * 32 + scol),
          (LV*)(lds + buf2 * 32768 + 16384 + h * 8192 + rb * 4096 + wv * 1024),
          16, 0, 0);
    }
  };

  stage_kh(0, 0, 0);
  stage_kh(0, 1, 0);
  asm volatile("s_waitcnt vmcnt(4)" ::: "memory");   // h0 landed; h1 in flight
  __builtin_amdgcn_sched_barrier(0);
  __builtin_amdgcn_s_barrier();

  const int NT = F_ / 64;
  for (int t = 0; t < NT; ++t) {
    const int buf = t & 1;
    const char* Lb = lds + buf * 32768;
    const bool pf = (t + 1 < NT);
    const int k1 = (t + 1) * 64;
    s16x8 af[4], bf[4];

    auto ldA = [&](int mf, int h) {
      return *(const s16x8*)(Lb + h * 8192 + (rA + mf * 16) * 64 + slot);
    };
    auto ldB = [&](int nf, int h) {
      return *(const s16x8*)(Lb + 16384 + h * 8192 + (rB + nf * 16) * 64 + slot);
    };

    // ---- phase 0: k-half 0 ; stage {A,B}_{t+1} h0 ----
#pragma unroll
    for (int nf = 0; nf < 4; ++nf) bf[nf] = ldB(nf, 0);
#pragma unroll
    for (int i = 0; i < 4; ++i) af[i] = ldA(i, 0);
    if (pf) stage_kh(buf ^ 1, 0, k1);
    __builtin_amdgcn_sched_barrier(0);
    __builtin_amdgcn_s_barrier();
    asm volatile("s_waitcnt lgkmcnt(0)" ::: "memory");
    __builtin_amdgcn_sched_barrier(0);
    __builtin_amdgcn_s_setprio(1);
#pragma unroll
    for (int i = 0; i < 4; ++i)
#pragma unroll
      for (int nf = 0; nf < 4; ++nf)
        acc[i][nf] = __builtin_amdgcn_mfma_f32_16x16x32_bf16(af[i], bf[nf], acc[i][nf], 0, 0, 0);
    __builtin_amdgcn_s_setprio(0);
    __builtin_amdgcn_sched_barrier(0);

    // ---- phase 1: wait own h1 writes, converge, k-half 1 ----
    if (pf) { asm volatile("s_waitcnt vmcnt(4)" ::: "memory"); }
    else    { asm volatile("s_waitcnt vmcnt(0)" ::: "memory"); }
    __builtin_amdgcn_sched_barrier(0);
    __builtin_amdgcn_s_barrier();                  // all waves' h1 visible
#pragma unroll
    for (int nf = 0; nf < 4; ++nf) bf[nf] = ldB(nf, 1);
#pragma unroll
    for (int i = 0; i < 4; ++i) af[i] = ldA(i, 1);
    if (pf) stage_kh(buf ^ 1, 1, k1);
    __builtin_amdgcn_sched_barrier(0);
    __builtin_amdgcn_s_barrier();
    asm volatile("s_waitcnt lgkmcnt(0)" ::: "memory");
    __builtin_amdgcn_sched_barrier(0);
    __builtin_amdgcn_s_setprio(1);
#pragma unroll
    for (int i = 0; i < 4; ++i)
#pragma unroll
      for (int nf = 0; nf < 4; ++nf)
        acc[i][nf] = __builtin_amdgcn_mfma_f32_16x16x32_bf16(af[i], bf[nf], acc[i][nf], 0, 0, 0);
    __builtin_amdgcn_s_setprio(0);
    __builtin_amdgcn_sched_barrier(0);

    if (pf) { asm volatile("s_waitcnt vmcnt(4)" ::: "memory"); }
    __builtin_amdgcn_sched_barrier(0);
    __builtin_amdgcn_s_barrier();
  }

  // ---- epilogue ----
#pragma unroll
  for (int nf = 0; nf < 4; ++nf) {
    int c = n0 + wn * 64 + nf * 16 + l15;
    float bv = bias ? bias[c] : 0.f;
#pragma unroll
    for (int mf = 0; mf < 4; ++mf) {
#pragma unroll
      for (int jj = 0; jj < 4; ++jj) {
        int r = m0 + wm * 64 + mf * 16 + l4 * 4 + jj;
        C[(size_t)r * F_ + c] = f2bf((acc[mf][nf][jj] + bv) * osc);
      }
    }
  }
}

// ---------------- flash attention v1 + XCD chunking (R15 exact) ----------
// Block: (64 q, 1 group) = 4 waves x 16 q, 256 thr, 72KB LDS -> 2 blocks/CU.
// KVBLK=64 dbuf global_load_lds; Q pre-scaled by (1/sqrt(128))*log2(e);
// T13 defer-max; T5 setprio; cvt_pk P pack. XCD-chunked 1D grid: 512 =
// 8 x 64, XCD c owns groups {2c,2c+1}.
__global__ __launch_bounds__(256, 2)
void attn_mfma(const unsigned short* __restrict__ Q,
               const unsigned short* __restrict__ K,
               const unsigned short* __restrict__ Vt,
               const float* __restrict__ vb,
               float* __restrict__ out) {
  __shared__ unsigned short Kt[2][64 * 128];
  __shared__ unsigned short Vts[2][128 * 64];
  __shared__ unsigned short Pt[4][16 * 64];
  const int tid = threadIdx.x, lane = tid & 63, wv = tid >> 6;
  const int l15 = lane & 15, l4 = lane >> 4;
  const int wg = (blockIdx.x & 7) * 64 + (blockIdx.x >> 3);
  const int g  = wg >> 5;
  const int q0 = (wg & 31) * 64 + wv * 16;

  s16x8 qa[4];
#pragma unroll
  for (int kc = 0; kc < 4; ++kc)
    qa[kc] = *(const s16x8*)(Q + (size_t)(q0 + l15) * F_ + g * DG_ + kc * 32 + l4 * 8);

  f32x4 oa[8];
#pragma unroll
  for (int df = 0; df < 8; ++df) oa[df] = (f32x4){0.f, 0.f, 0.f, 0.f};
  float m_r = -1e30f, l_r = 0.f;

  const int ksw0 = (((lane & 15) ^ (lane >> 4)) * 8);
  const int ksw1 = (((lane & 15) ^ 4 ^ (lane >> 4)) * 8);
  const int vsw  = (((lane & 7) ^ (lane >> 3)) * 8);
  const int xorb = (l15 & 7) << 4;
  int csw[4];
#pragma unroll
  for (int kc = 0; kc < 4; ++kc) csw[kc] = (kc * 64 + l4 * 16) ^ xorb;

  auto stage = [&](int buf, int kv0) {
#pragma unroll
    for (int i = 0; i < 4; ++i) {   // K tile: 4 rows (256B) per instr
      int r0 = wv * 16 + i * 4;
      __builtin_amdgcn_global_load_lds(
          (GV*)(K + (size_t)(kv0 + r0 + (lane >> 4)) * F_ + g * DG_ + ((i & 1) ? ksw1 : ksw0)),
          (LV*)(&Kt[buf][r0 * 128]), 16, 0, 0);
    }
#pragma unroll
    for (int i = 0; i < 4; ++i) {   // V^T tile: 8 rows (128B) per instr
      int r0 = wv * 32 + i * 8;
      __builtin_amdgcn_global_load_lds(
          (GV*)(Vt + (size_t)(g * DG_ + r0 + (lane >> 3)) * M_ + kv0 + vsw),
          (LV*)(&Vts[buf][r0 * 64]), 16, 0, 0);
    }
  };

  stage(0, 0);
  __syncthreads();
  int cur = 0;
  unsigned short* Pw = &Pt[wv][0];

  for (int t = 0; t < M_ / 64; ++t) {
    if (t + 1 < M_ / 64) stage(cur ^ 1, (t + 1) * 64);
    const unsigned short* Kb = &Kt[cur][0];
    const unsigned short* Vb = &Vts[cur][0];

    // ---- S^T = K Q^T : lane q=l15, kv = kvf*16 + l4*4 + j (log2 domain) --
    f32x4 sf[4];
    __builtin_amdgcn_s_setprio(1);
#pragma unroll
    for (int kvf = 0; kvf < 4; ++kvf) {
      f32x4 s = (f32x4){0.f, 0.f, 0.f, 0.f};
#pragma unroll
      for (int kc = 0; kc < 4; ++kc) {
        s16x8 kf = *(const s16x8*)((const char*)Kb + (kvf * 16 + l15) * 256 + csw[kc]);
        s = __builtin_amdgcn_mfma_f32_16x16x32_bf16(kf, qa[kc], s, 0, 0, 0);
      }
      sf[kvf] = s;
    }
    __builtin_amdgcn_s_setprio(0);

    // ---- online softmax with defer-max (THR=8, log2 domain) ----
    float tmax = sf[0][0];
#pragma unroll
    for (int kvf = 0; kvf < 4; ++kvf) {
      tmax = fmaxf(tmax, fmaxf(fmaxf(sf[kvf][0], sf[kvf][1]),
                               fmaxf(sf[kvf][2], sf[kvf][3])));
    }
    tmax = fmaxf(tmax, __shfl_xor(tmax, 16));
    tmax = fmaxf(tmax, __shfl_xor(tmax, 32));
    if (!__all(tmax <= m_r + 8.0f)) {
      float mnew = fmaxf(m_r, tmax);
      float corr = __builtin_amdgcn_exp2f(m_r - mnew);
      m_r = mnew;
      l_r *= corr;
      float c0 = __shfl(corr, l4 * 4 + 0);
      float c1 = __shfl(corr, l4 * 4 + 1);
      float c2 = __shfl(corr, l4 * 4 + 2);
      float c3 = __shfl(corr, l4 * 4 + 3);
#pragma unroll
      for (int df = 0; df < 8; ++df) {
        oa[df][0] *= c0; oa[df][1] *= c1; oa[df][2] *= c2; oa[df][3] *= c3;
      }
    }

    float psum = 0.f;
#pragma unroll
    for (int kvf = 0; kvf < 4; ++kvf) {
      float p0 = __builtin_amdgcn_exp2f(sf[kvf][0] - m_r);
      float p1 = __builtin_amdgcn_exp2f(sf[kvf][1] - m_r);
      float p2 = __builtin_amdgcn_exp2f(sf[kvf][2] - m_r);
      float p3 = __builtin_amdgcn_exp2f(sf[kvf][3] - m_r);
      psum += (p0 + p1) + (p2 + p3);
      u32x2 w;
      asm("v_cvt_pk_bf16_f32 %0, %1, %2" : "=v"(w.x) : "v"(p0), "v"(p1));
      asm("v_cvt_pk_bf16_f32 %0, %1, %2" : "=v"(w.y) : "v"(p2), "v"(p3));
      *(u32x2*)((char*)Pw + l15 * 128 + ((kvf * 32 + l4 * 8) ^ xorb)) = w;
    }
    psum += __shfl_xor(psum, 16);
    psum += __shfl_xor(psum, 32);
    l_r += psum;

    // ---- O += P V : A = P rows (q=l15), B = V^T rows (d) ----
    s16x8 pa0 = *(const s16x8*)((const char*)Pw + l15 * 128 + csw[0]);
    s16x8 pa1 = *(const s16x8*)((const char*)Pw + l15 * 128 + csw[1]);
    __builtin_amdgcn_s_setprio(1);
#pragma unroll
    for (int df = 0; df < 8; ++df) {
      s16x8 v0 = *(const s16x8*)((const char*)Vb + (df * 16 + l15) * 128 + csw[0]);
      s16x8 v1 = *(const s16x8*)((const char*)Vb + (df * 16 + l15) * 128 + csw[1]);
      oa[df] = __builtin_amdgcn_mfma_f32_16x16x32_bf16(pa0, v0, oa[df], 0, 0, 0);
      oa[df] = __builtin_amdgcn_mfma_f32_16x16x32_bf16(pa1, v1, oa[df], 0, 0, 0);
    }
    __builtin_amdgcn_s_setprio(0);
    __syncthreads();
    cur ^= 1;
  }

  // ---- epilogue ----
  float linv = 1.0f / l_r;
  float i0 = __shfl(linv, l4 * 4 + 0);
  float i1 = __shfl(linv, l4 * 4 + 1);
  float i2 = __shfl(linv, l4 * 4 + 2);
  float i3 = __shfl(linv, l4 * 4 + 3);
#pragma unroll
  for (int df = 0; df < 8; ++df) {
    int c = g * DG_ + df * 16 + l15;
    float bv = vb[c];
    out[(size_t)(q0 + l4 * 4 + 0) * F_ + c] = oa[df][0] * i0 + bv;
    out[(size_t)(q0 + l4 * 4 + 1) * F_ + c] = oa[df][1] * i1 + bv;
    out[(size_t)(q0 + l4 * 4 + 2) * F_ + c] = oa[df][2] * i2 + bv;
    out[(size_t)(q0 + l4 * 4 + 3) * F_ + c] = oa[df][3] * i3 + bv;
  }
}

extern "C" void kernel_launch(void* const* d_in, const int* in_sizes, int n_in,
                              void* d_out, int out_size, void* d_ws, size_t ws_size,
                              hipStream_t stream) {
  const float* roi  = (const float*)d_in[0];
  const float* ref  = (const float*)d_in[1];
  const float* Wq_w = (const float*)d_in[2];
  const float* Wq_b = (const float*)d_in[3];
  const float* Wk_w = (const float*)d_in[4];
  const float* Wk_b = (const float*)d_in[5];
  const float* Wv_w = (const float*)d_in[6];
  const float* Wv_b = (const float*)d_in[7];
  float* out = (float*)d_out;
  const size_t SEG = 4194304;  // 8 MB / 2B
  const float cscale = 0.12751664508246770f;  // (1/sqrt(128)) * log2(e)

  if (ws_size < 64ull * 1024 * 1024) return;
  unsigned short* roi_bf = (unsigned short*)d_ws;
  unsigned short* ref_bf = roi_bf + SEG;
  unsigned short* Wq_bf  = ref_bf + SEG;
  unsigned short* Wk_bf  = Wq_bf + SEG;
  unsigned short* Wv_bf  = Wk_bf + SEG;
  unsigned short* Qb     = Wv_bf + SEG;
  unsigned short* Kb     = Qb + SEG;
  unsigned short* Vtb    = Kb + SEG;

  Cvt5Args ca;
  ca.s[0] = roi;  ca.d[0] = roi_bf;
  ca.s[1] = ref;  ca.d[1] = ref_bf;
  ca.s[2] = Wq_w; ca.d[2] = Wq_bf;
  ca.s[3] = Wk_w; ca.d[3] = Wk_bf;
  ca.s[4] = Wv_w; ca.d[4] = Wv_bf;
  cvt5<<<10240, 256, 0, stream>>>(ca);

  GemmJobs jb;
  jb.A[0] = roi_bf; jb.B[0] = Wq_bf;  jb.bias[0] = Wq_b;    jb.C[0] = Qb;  jb.osc[0] = cscale;
  jb.A[1] = ref_bf; jb.B[1] = Wk_bf;  jb.bias[1] = Wk_b;    jb.C[1] = Kb;  jb.osc[1] = 1.0f;
  jb.A[2] = Wv_bf;  jb.B[2] = ref_bf; jb.bias[2] = nullptr; jb.C[2] = Vtb; jb.osc[2] = 1.0f;
  gemm128<<<768, 256, 0, stream>>>(jb);

  attn_mfma<<<512, 256, 0, stream>>>(Qb, Kb, Vtb, Wv_b, out);
}